// Round 7
// baseline (145.220 us; speedup 1.0000x reference)
//
#include <hip/hip_runtime.h>

// Problem constants
#define Jd   128   // feature dim
#define Cn   512   // num classes
#define TLn  16    // label seq length
#define Bn   32    // batch

// ---------------------------------------------------------------------------
// Reduction (x, lens dead; batch-uniform trajectory):
//   LT [tau][k][c] = L[c,tau,k]          l2T[tau][c] = ||L[c,tau,:]||^2
//   PLT[tau][j][c] = sum_k W[k][j]*L[c,tau,k]          ( = (L@W)^T )
//   S0[c]          = ||sos@W - L[c,0,:]||^2
//   DOT[s][tau][c] = l2T[tau][c] - 2*sum_j PLT[tau][j][s]*LT[tau][j][c]
//   s_0 = argmin S0;  s_t = argmin_c sum_{tau<t} DOT[s_{t-1}][tau][c]
//   out = [ broadcast_B(s_16) | broadcast_B(PLT[:, :, s_15]) ]
// Round-17: evidence from r12/r13/r16 — k_dot perf tracks occupancy, not
// LDS-read count (direct-A cut 1/3 of LDS ops: neutral). So k_dot is
// stage/barrier-latency bound. This round: k_dot goes FULLY LDS-free.
// A: 16-lane-broadcast dwordx4 (64B/cacheline per wave per j). B: whole wave
// reads the same two 256B row segments per j (L1/L2 broadcast; each LT row
// reused by 8 s-tile blocks). No staging, no barriers -> occupancy VGPR-
// bound (~5-6 blocks/CU = 20-24 waves/CU vs 12). j loop = one ascending
// 0..127 fmaf chain, identical float sequence -> absmax stays 0.
// ---------------------------------------------------------------------------

__device__ __forceinline__ unsigned int f2ord(float f) {
    unsigned int u = __float_as_uint(f);
    return (u & 0x80000000u) ? ~u : (u | 0x80000000u);   // monotone total order
}
__device__ __forceinline__ unsigned long long packkey(float v, int c) {
    return ((unsigned long long)f2ord(v) << 32) | (unsigned int)c;
}

// grid = 512 x 256: bid -> tau = bid&15, jh = (bid>>4)&1 (j-half), ct = bid>>5
// (16 c-tiles of 32). Produces PLT[tau][jh*64..+63][c-tile]; jh==0 blocks also
// emit LT + l2T for their c-tile.
__global__ void __launch_bounds__(256, 4)
k_prep3(const float* __restrict__ L, const float* __restrict__ W,
        float* __restrict__ LT, float* __restrict__ l2T,
        float* __restrict__ PLT) {
    __shared__ float Lst[128][36];               // 18 KB transposed L tile [k][c]
    __shared__ float Ws[128][68];                // 34 KB W half [k][j-j0]
    int tid = threadIdx.x, bid = blockIdx.x;
    int tau = bid & 15, jh = (bid >> 4) & 1, c0 = (bid >> 5) * 32;
    int j0 = jh * 64;

    // --- stage Lst (transpose 32 L-rows; coalesced global reads) + l2 ---
    int cr = tid >> 3, oc = tid & 7;             // c-row 0..31, octant
    const float4* src = (const float4*)(L + ((size_t)(c0 + cr) * TLn + tau) * Jd);
    float l2p = 0.f;
    #pragma unroll
    for (int i = 0; i < 4; ++i) {
        float4 v = src[oc * 4 + i];
        int kb = (oc * 4 + i) * 4;
        Lst[kb + 0][cr] = v.x;  Lst[kb + 1][cr] = v.y;
        Lst[kb + 2][cr] = v.z;  Lst[kb + 3][cr] = v.w;
        l2p += v.x * v.x + v.y * v.y + v.z * v.z + v.w * v.w;
    }
    l2p += __shfl_down(l2p, 4, 8);               // reduce over octant (8 lanes/c)
    l2p += __shfl_down(l2p, 2, 8);
    l2p += __shfl_down(l2p, 1, 8);
    if (oc == 0 && jh == 0) l2T[tau * Cn + c0 + cr] = l2p;

    // --- stage Ws: W[k][j0..j0+63], straight coalesced copy ---
    #pragma unroll
    for (int r = 0; r < 8; ++r) {
        int idx = r * 256 + tid;                 // 0..2047 float4s
        int k = idx >> 4, f = idx & 15;
        *(float4*)&Ws[k][f * 4] = *(const float4*)(W + (size_t)k * Jd + j0 + f * 4);
    }
    __syncthreads();

    int c = tid & 31, jq = tid >> 5;             // c lane (coalesced), 8 j-groups

    // --- LT emit (jh==0 only): b32 reads conflict-free, 128B-chunk stores ---
    if (jh == 0) {
        #pragma unroll
        for (int k = jq; k < Jd; k += 8)
            LT[((size_t)tau * Jd + k) * Cn + c0 + c] = Lst[k][c];
    }

    // --- GEMM: PLT[tau][j0+jq*8+i][c0+c] = sum_k Ws[k][jq*8+i] * Lst[k][c] ---
    float acc[8] = {};
    #pragma unroll 4
    for (int k = 0; k < Jd; ++k) {               // ascending k: same sum order
        float a = Lst[k][c];                     // b32, banks all distinct (pitch 36)
        float4 w0 = *(const float4*)&Ws[k][jq * 8];      // 32-lane broadcast b128
        float4 w1 = *(const float4*)&Ws[k][jq * 8 + 4];
        acc[0] = fmaf(a, w0.x, acc[0]);
        acc[1] = fmaf(a, w0.y, acc[1]);
        acc[2] = fmaf(a, w0.z, acc[2]);
        acc[3] = fmaf(a, w0.w, acc[3]);
        acc[4] = fmaf(a, w1.x, acc[4]);
        acc[5] = fmaf(a, w1.y, acc[5]);
        acc[6] = fmaf(a, w1.z, acc[6]);
        acc[7] = fmaf(a, w1.w, acc[7]);
    }
    #pragma unroll
    for (int i = 0; i < 8; ++i)                  // two 128B chunks per store inst
        PLT[((size_t)tau * Jd + j0 + jq * 8 + i) * Cn + c0 + c] = acc[i];
}

// grid = 513 x 256. bid<512: tau = bid&15, st = (bid>>4)&7 (64 s),
// cq = bid>>7 (128 c). NO LDS, NO BARRIERS: A and B both read direct from
// global per j (A: 64B bcast/wave; B: two 256B segments shared wave-wide,
// L1/L2-served, 8-block reuse per LT row). One ascending j=0..127 chain,
// micro 4s x 8c, 3 b128 loads per 32 fmaf. bid==512: S0.
__global__ void __launch_bounds__(256, 4)
k_dot(const float* __restrict__ LT, const float* __restrict__ PLT,
      const float* __restrict__ l2T,
      const float* __restrict__ sos, const float* __restrict__ W,
      float* __restrict__ DOT, float* __restrict__ S0) {
    __shared__ float pred0s[Jd];                 // S0 path only (512 B)
    int tid = threadIdx.x, bid = blockIdx.x;

    if (bid == 512) {                            // ---- S0 path ----
        if (tid < Jd) {
            float a = 0.f;
            for (int k = 0; k < Jd; ++k) a = fmaf(sos[k], W[k * Jd + tid], a);
            pred0s[tid] = a;
        }
        __syncthreads();
        float a0 = 0.f, a1 = 0.f;
        for (int jj = 0; jj < Jd; ++jj) {
            float p = pred0s[jj];
            float d0 = p - LT[(size_t)jj * Cn + tid];        // tau = 0 plane
            float d1 = p - LT[(size_t)jj * Cn + tid + 256];
            a0 = fmaf(d0, d0, a0);
            a1 = fmaf(d1, d1, a1);
        }
        S0[tid] = a0;  S0[tid + 256] = a1;
        return;
    }

    int tau = bid & 15, st = (bid >> 4) & 7, cq = bid >> 7;
    int s0 = st * 64, c0 = cq * 128;
    int sg = tid >> 4, cg = tid & 15;            // 16x16 threads

    const float* Abase = PLT + (size_t)tau * Jd * Cn + s0 + sg * 4;
    const float* Bbase = LT  + (size_t)tau * Jd * Cn + c0 + cg * 4;

    float acc[4][8] = {};                        // 4 s x (4+4) c
    #pragma unroll 4
    for (int j = 0; j < Jd; ++j) {               // ascending j: same sum order
        float4 a  = *(const float4*)(Abase + (size_t)j * Cn);       // 64B bcast
        float4 b0 = *(const float4*)(Bbase + (size_t)j * Cn);       // 256B seg
        float4 b1 = *(const float4*)(Bbase + (size_t)j * Cn + 64);  // 256B seg
        float av[4] = {a.x, a.y, a.z, a.w};
        float bv[8] = {b0.x, b0.y, b0.z, b0.w, b1.x, b1.y, b1.z, b1.w};
        #pragma unroll
        for (int i = 0; i < 4; ++i)
            #pragma unroll
            for (int q = 0; q < 8; ++q)
                acc[i][q] = fmaf(av[i], bv[q], acc[i][q]);
    }

    float4 l2a = *(const float4*)(l2T + tau * Cn + c0 + cg * 4);
    float4 l2b = *(const float4*)(l2T + tau * Cn + c0 + 64 + cg * 4);
    #pragma unroll
    for (int i = 0; i < 4; ++i) {
        int s = s0 + sg * 4 + i;
        float* dst = DOT + ((size_t)s * TLn + tau) * Cn + c0;
        float4 v0 = {l2a.x - 2.f * acc[i][0], l2a.y - 2.f * acc[i][1],
                     l2a.z - 2.f * acc[i][2], l2a.w - 2.f * acc[i][3]};
        float4 v1 = {l2b.x - 2.f * acc[i][4], l2b.y - 2.f * acc[i][5],
                     l2b.z - 2.f * acc[i][6], l2b.w - 2.f * acc[i][7]};
        *(float4*)(dst + cg * 4) = v0;           // 256B contiguous per 16 lanes
        *(float4*)(dst + 64 + cg * 4) = v1;
    }
}

// 1 block x 64 (single wave): 17-step argmin chain, float4 loads (8 c per
// lane), no barriers/LDS — pure in-wave shuffle reduce. Same masked-fmaf
// chain per c (ascending tau) and same packkey tie-break as before.
__global__ void k_seq(const float* __restrict__ S0, const float* __restrict__ DOT,
                      int* __restrict__ keys) {
    int lane = threadIdx.x;                      // 0..63
    int sCur = 0;

    for (int t = 0; t <= TLn; ++t) {
        unsigned long long m;
        if (t == 0) {
            float4 v0 = *(const float4*)(S0 + lane * 4);
            float4 v1 = *(const float4*)(S0 + 256 + lane * 4);
            float v[8] = {v0.x, v0.y, v0.z, v0.w, v1.x, v1.y, v1.z, v1.w};
            m = packkey(v[0], lane * 4);
            #pragma unroll
            for (int i = 1; i < 8; ++i) {
                int c = (i < 4) ? (lane * 4 + i) : (256 + lane * 4 + (i - 4));
                unsigned long long k2 = packkey(v[i], c);
                if (k2 < m) m = k2;
            }
        } else {
            const float* base = DOT + (size_t)sCur * TLn * Cn;
            float4 s0v = {0.f, 0.f, 0.f, 0.f}, s1v = {0.f, 0.f, 0.f, 0.f};
            #pragma unroll
            for (int tau = 0; tau < TLn; ++tau) {            // 32 independent b128
                float4 w0 = *(const float4*)(base + (size_t)tau * Cn + lane * 4);
                float4 w1 = *(const float4*)(base + (size_t)tau * Cn + 256 + lane * 4);
                float mk = (tau < t) ? 1.f : 0.f;            // ascending tau chain
                s0v.x = fmaf(w0.x, mk, s0v.x);  s0v.y = fmaf(w0.y, mk, s0v.y);
                s0v.z = fmaf(w0.z, mk, s0v.z);  s0v.w = fmaf(w0.w, mk, s0v.w);
                s1v.x = fmaf(w1.x, mk, s1v.x);  s1v.y = fmaf(w1.y, mk, s1v.y);
                s1v.z = fmaf(w1.z, mk, s1v.z);  s1v.w = fmaf(w1.w, mk, s1v.w);
            }
            float v[8] = {s0v.x, s0v.y, s0v.z, s0v.w, s1v.x, s1v.y, s1v.z, s1v.w};
            m = packkey(v[0], lane * 4);
            #pragma unroll
            for (int i = 1; i < 8; ++i) {
                int c = (i < 4) ? (lane * 4 + i) : (256 + lane * 4 + (i - 4));
                unsigned long long k2 = packkey(v[i], c);
                if (k2 < m) m = k2;
            }
        }
        #pragma unroll
        for (int o = 32; o; o >>= 1) {
            unsigned long long o2 = __shfl_down(m, o, 64);
            if (o2 < m) m = o2;
        }
        m = __shfl(m, 0, 64);                    // broadcast winner to all lanes
        sCur = (int)(m & 0xFFFFFFFFull);
        if (lane == 0) keys[t] = sCur;
    }
}

// grid = 512 x 128: out = [sofar(32) | pls(B,TL,J)]; bt = b*TLn+tau.
// PLT gathers are L2-broadcast across the 32 b-copies; stores coalesced.
__global__ void k_out(const float* __restrict__ PLT, const int* __restrict__ keys,
                      float* __restrict__ out) {
    int bt = blockIdx.x, j = threadIdx.x, tau = bt & (TLn - 1);
    int s16 = keys[TLn], s15 = keys[TLn - 1];
    out[Bn + (size_t)bt * Jd + j] = PLT[((size_t)tau * Jd + j) * Cn + s15];
    if (bt == 0 && j < Bn) out[j] = (float)s16;
}

extern "C" void kernel_launch(void* const* d_in, const int* in_sizes, int n_in,
                              void* d_out, int out_size, void* d_ws, size_t ws_size,
                              hipStream_t stream) {
    // inputs: 0:x (dead, 32MB), 1:lens (dead), 2:sos, 3:label_seqs, 4:W  (all f32)
    const float* sos = (const float*)d_in[2];
    const float* L   = (const float*)d_in[3];
    const float* W   = (const float*)d_in[4];
    float* out = (float*)d_out;

    // ws: S0(2KB)@0 | keys@2048 | l2T(32KB)@4K | PLT(4MB)@64K | LT(4MB) | DOT(16.8MB)
    const size_t l2Off  = 4096;
    const size_t pltOff = 65536;
    const size_t ltOff  = pltOff + (size_t)TLn * Jd * Cn * sizeof(float);
    const size_t dotOff = ltOff  + (size_t)TLn * Jd * Cn * sizeof(float);
    const size_t need   = dotOff + (size_t)Cn * TLn * Cn * sizeof(float);  // ~25 MB
    char* base = (ws_size >= need) ? (char*)d_ws : (char*)d_in[0];  // x dead, 32 MB
    float* S0   = (float*)base;
    int*   keys = (int*)(base + 2048);
    float* l2T  = (float*)(base + l2Off);
    float* PLT  = (float*)(base + pltOff);
    float* LT   = (float*)(base + ltOff);
    float* DOT  = (float*)(base + dotOff);

    hipLaunchKernelGGL(k_prep3, dim3(512), dim3(256), 0, stream, L, W, LT, l2T, PLT);
    hipLaunchKernelGGL(k_dot,   dim3(513), dim3(256), 0, stream,
                       LT, PLT, l2T, sos, W, DOT, S0);
    hipLaunchKernelGGL(k_seq,   dim3(1),   dim3(64), 0, stream, S0, DOT, keys);
    hipLaunchKernelGGL(k_out,   dim3(Bn * TLn), dim3(Jd), 0, stream, PLT, keys, out);
}

// Round 8
// 126.116 us; speedup vs baseline: 1.1515x; 1.1515x over previous
//
#include <hip/hip_runtime.h>

// Problem constants
#define Jd   128   // feature dim
#define Cn   512   // num classes
#define TLn  16    // label seq length
#define Bn   32    // batch

// ---------------------------------------------------------------------------
// Reduction (x, lens dead; batch-uniform trajectory):
//   LT [tau][k][c] = L[c,tau,k]          l2T[tau][c] = ||L[c,tau,:]||^2
//   PLT[tau][j][c] = sum_k W[k][j]*L[c,tau,k]          ( = (L@W)^T )
//   S0[c]          = ||sos@W - L[c,0,:]||^2
//   DOT[s][tau][c] = l2T[tau][c] - 2*sum_j PLT[tau][j][s]*LT[tau][j][c]
//   s_0 = argmin S0;  s_t = argmin_c sum_{tau<t} DOT[s_{t-1}][tau][c]
//   out = [ broadcast_B(s_16) | broadcast_B(PLT[:, :, s_15]) ]
// Round-18: k_dot experiment series closed (r12/13/16/17 all <= baseline;
// no-LDS was -20us: B staging is load-bearing). k_dot/k_prep3 reverted to
// the exact 122.3us baseline. This round attacks the ~28us inter-dispatch
// gap budget: merge k_seq+k_out into ONE ordinary kernel k_finish (grid 1,
// 256t): wave0 runs the proven barrier-free chain, __syncthreads (block-
// local, NOT grid sync - r14's 30us coop barrier is avoided), then 4 waves
// do the gathered output write. 4 launches -> 3. All fmaf chains and values
// unchanged -> absmax stays 0.
// ---------------------------------------------------------------------------

__device__ __forceinline__ unsigned int f2ord(float f) {
    unsigned int u = __float_as_uint(f);
    return (u & 0x80000000u) ? ~u : (u | 0x80000000u);   // monotone total order
}
__device__ __forceinline__ unsigned long long packkey(float v, int c) {
    return ((unsigned long long)f2ord(v) << 32) | (unsigned int)c;
}

// grid = 512 x 256: bid -> tau = bid&15, jh = (bid>>4)&1 (j-half), ct = bid>>5
// (16 c-tiles of 32). Produces PLT[tau][jh*64..+63][c-tile]; jh==0 blocks also
// emit LT + l2T for their c-tile.
__global__ void __launch_bounds__(256, 4)
k_prep3(const float* __restrict__ L, const float* __restrict__ W,
        float* __restrict__ LT, float* __restrict__ l2T,
        float* __restrict__ PLT) {
    __shared__ float Lst[128][36];               // 18 KB transposed L tile [k][c]
    __shared__ float Ws[128][68];                // 34 KB W half [k][j-j0]
    int tid = threadIdx.x, bid = blockIdx.x;
    int tau = bid & 15, jh = (bid >> 4) & 1, c0 = (bid >> 5) * 32;
    int j0 = jh * 64;

    // --- stage Lst (transpose 32 L-rows; coalesced global reads) + l2 ---
    int cr = tid >> 3, oc = tid & 7;             // c-row 0..31, octant
    const float4* src = (const float4*)(L + ((size_t)(c0 + cr) * TLn + tau) * Jd);
    float l2p = 0.f;
    #pragma unroll
    for (int i = 0; i < 4; ++i) {
        float4 v = src[oc * 4 + i];
        int kb = (oc * 4 + i) * 4;
        Lst[kb + 0][cr] = v.x;  Lst[kb + 1][cr] = v.y;
        Lst[kb + 2][cr] = v.z;  Lst[kb + 3][cr] = v.w;
        l2p += v.x * v.x + v.y * v.y + v.z * v.z + v.w * v.w;
    }
    l2p += __shfl_down(l2p, 4, 8);               // reduce over octant (8 lanes/c)
    l2p += __shfl_down(l2p, 2, 8);
    l2p += __shfl_down(l2p, 1, 8);
    if (oc == 0 && jh == 0) l2T[tau * Cn + c0 + cr] = l2p;

    // --- stage Ws: W[k][j0..j0+63], straight coalesced copy ---
    #pragma unroll
    for (int r = 0; r < 8; ++r) {
        int idx = r * 256 + tid;                 // 0..2047 float4s
        int k = idx >> 4, f = idx & 15;
        *(float4*)&Ws[k][f * 4] = *(const float4*)(W + (size_t)k * Jd + j0 + f * 4);
    }
    __syncthreads();

    int c = tid & 31, jq = tid >> 5;             // c lane (coalesced), 8 j-groups

    // --- LT emit (jh==0 only): b32 reads conflict-free, 128B-chunk stores ---
    if (jh == 0) {
        #pragma unroll
        for (int k = jq; k < Jd; k += 8)
            LT[((size_t)tau * Jd + k) * Cn + c0 + c] = Lst[k][c];
    }

    // --- GEMM: PLT[tau][j0+jq*8+i][c0+c] = sum_k Ws[k][jq*8+i] * Lst[k][c] ---
    float acc[8] = {};
    #pragma unroll 4
    for (int k = 0; k < Jd; ++k) {               // ascending k: same sum order
        float a = Lst[k][c];                     // b32, banks all distinct (pitch 36)
        float4 w0 = *(const float4*)&Ws[k][jq * 8];      // 32-lane broadcast b128
        float4 w1 = *(const float4*)&Ws[k][jq * 8 + 4];
        acc[0] = fmaf(a, w0.x, acc[0]);
        acc[1] = fmaf(a, w0.y, acc[1]);
        acc[2] = fmaf(a, w0.z, acc[2]);
        acc[3] = fmaf(a, w0.w, acc[3]);
        acc[4] = fmaf(a, w1.x, acc[4]);
        acc[5] = fmaf(a, w1.y, acc[5]);
        acc[6] = fmaf(a, w1.z, acc[6]);
        acc[7] = fmaf(a, w1.w, acc[7]);
    }
    #pragma unroll
    for (int i = 0; i < 8; ++i)                  // two 128B chunks per store inst
        PLT[((size_t)tau * Jd + j0 + jq * 8 + i) * Cn + c0 + c] = acc[i];
}

// grid = 513 x 256, LDS-staged GEMM, 3 blocks/CU (144KB LDS). bid<512:
// tau = bid&15, st = (bid>>4)&7 (64 s), cq = bid>>7 (128 c). K in 2 j-halves;
// micro 4s x 8c. bid==512: S0.   [exact baseline structure, 122.3us verified]
__global__ void __launch_bounds__(256, 3)
k_dot(const float* __restrict__ LT, const float* __restrict__ PLT,
      const float* __restrict__ l2T,
      const float* __restrict__ sos, const float* __restrict__ W,
      float* __restrict__ DOT, float* __restrict__ S0) {
    __shared__ float As[64][64];                 // 16 KB  [j][s]
    __shared__ float Bs[64][128];                // 32 KB  [j][c]
    int tid = threadIdx.x, bid = blockIdx.x;

    if (bid == 512) {                            // ---- S0 path ----
        float* pred0 = &As[0][0];
        if (tid < Jd) {
            float a = 0.f;
            for (int k = 0; k < Jd; ++k) a = fmaf(sos[k], W[k * Jd + tid], a);
            pred0[tid] = a;
        }
        __syncthreads();
        float a0 = 0.f, a1 = 0.f;
        for (int jj = 0; jj < Jd; ++jj) {
            float p = pred0[jj];
            float d0 = p - LT[(size_t)jj * Cn + tid];        // tau = 0 plane
            float d1 = p - LT[(size_t)jj * Cn + tid + 256];
            a0 = fmaf(d0, d0, a0);
            a1 = fmaf(d1, d1, a1);
        }
        S0[tid] = a0;  S0[tid + 256] = a1;
        return;
    }

    int tau = bid & 15, st = (bid >> 4) & 7, cq = bid >> 7;
    int s0 = st * 64, c0 = cq * 128;
    int sg = tid >> 4, cg = tid & 15;            // 16x16 threads

    float acc[4][8] = {};                        // 4 s x (4+4) c
    for (int h = 0; h < 2; ++h) {                // j-halves
        __syncthreads();
        // stage A half: 64 j-rows x 64 s  (coalesced global, conflict-free LDS)
        const float4* Asrc = (const float4*)(PLT + ((size_t)tau * Jd + h * 64) * Cn + s0);
        #pragma unroll
        for (int i = 0; i < 4; ++i) {
            int flat = i * 256 + tid;            // 0..1023 float4s
            int row = flat >> 4, col = flat & 15;
            *(float4*)&As[row][col * 4] = Asrc[(size_t)row * (Cn / 4) + col];
        }
        // stage B half: 64 j-rows x 128 c
        const float4* Bsrc = (const float4*)(LT + ((size_t)tau * Jd + h * 64) * Cn + c0);
        #pragma unroll
        for (int i = 0; i < 8; ++i) {
            int flat = i * 256 + tid;            // 0..2047 float4s
            int row = flat >> 5, col = flat & 31;
            *(float4*)&Bs[row][col * 4] = Bsrc[(size_t)row * (Cn / 4) + col];
        }
        __syncthreads();
        #pragma unroll 4
        for (int j = 0; j < 64; ++j) {           // ascending j: same sum order
            float4 a  = *(const float4*)&As[j][sg * 4];       // broadcast, no conflict
            float4 b0 = *(const float4*)&Bs[j][cg * 4];       // 2-way (free)
            float4 b1 = *(const float4*)&Bs[j][64 + cg * 4];  // 2-way (free)
            float av[4] = {a.x, a.y, a.z, a.w};
            float bv[8] = {b0.x, b0.y, b0.z, b0.w, b1.x, b1.y, b1.z, b1.w};
            #pragma unroll
            for (int i = 0; i < 4; ++i)
                #pragma unroll
                for (int q = 0; q < 8; ++q)
                    acc[i][q] = fmaf(av[i], bv[q], acc[i][q]);
        }
    }

    float4 l2a = *(const float4*)(l2T + tau * Cn + c0 + cg * 4);
    float4 l2b = *(const float4*)(l2T + tau * Cn + c0 + 64 + cg * 4);
    #pragma unroll
    for (int i = 0; i < 4; ++i) {
        int s = s0 + sg * 4 + i;
        float* dst = DOT + ((size_t)s * TLn + tau) * Cn + c0;
        float4 v0 = {l2a.x - 2.f * acc[i][0], l2a.y - 2.f * acc[i][1],
                     l2a.z - 2.f * acc[i][2], l2a.w - 2.f * acc[i][3]};
        float4 v1 = {l2b.x - 2.f * acc[i][4], l2b.y - 2.f * acc[i][5],
                     l2b.z - 2.f * acc[i][6], l2b.w - 2.f * acc[i][7]};
        *(float4*)(dst + cg * 4) = v0;           // 256B contiguous per 16 lanes
        *(float4*)(dst + 64 + cg * 4) = v1;
    }
}

// Single-wave argmin chain (proven absmax-0): 17 steps, float4 loads (8 c
// per lane), no barriers/LDS, pure in-wave shuffle reduce.
__device__ __forceinline__ void seq_chain(const float* __restrict__ S0,
                                          const float* __restrict__ DOT,
                                          int* __restrict__ keys) {
    int lane = threadIdx.x;                      // 0..63
    int sCur = 0;
    for (int t = 0; t <= TLn; ++t) {
        unsigned long long m;
        if (t == 0) {
            float4 v0 = *(const float4*)(S0 + lane * 4);
            float4 v1 = *(const float4*)(S0 + 256 + lane * 4);
            float v[8] = {v0.x, v0.y, v0.z, v0.w, v1.x, v1.y, v1.z, v1.w};
            m = packkey(v[0], lane * 4);
            #pragma unroll
            for (int i = 1; i < 8; ++i) {
                int c = (i < 4) ? (lane * 4 + i) : (256 + lane * 4 + (i - 4));
                unsigned long long k2 = packkey(v[i], c);
                if (k2 < m) m = k2;
            }
        } else {
            const float* base = DOT + (size_t)sCur * TLn * Cn;
            float4 s0v = {0.f, 0.f, 0.f, 0.f}, s1v = {0.f, 0.f, 0.f, 0.f};
            #pragma unroll
            for (int tau = 0; tau < TLn; ++tau) {            // 32 independent b128
                float4 w0 = *(const float4*)(base + (size_t)tau * Cn + lane * 4);
                float4 w1 = *(const float4*)(base + (size_t)tau * Cn + 256 + lane * 4);
                float mk = (tau < t) ? 1.f : 0.f;            // ascending tau chain
                s0v.x = fmaf(w0.x, mk, s0v.x);  s0v.y = fmaf(w0.y, mk, s0v.y);
                s0v.z = fmaf(w0.z, mk, s0v.z);  s0v.w = fmaf(w0.w, mk, s0v.w);
                s1v.x = fmaf(w1.x, mk, s1v.x);  s1v.y = fmaf(w1.y, mk, s1v.y);
                s1v.z = fmaf(w1.z, mk, s1v.z);  s1v.w = fmaf(w1.w, mk, s1v.w);
            }
            float v[8] = {s0v.x, s0v.y, s0v.z, s0v.w, s1v.x, s1v.y, s1v.z, s1v.w};
            m = packkey(v[0], lane * 4);
            #pragma unroll
            for (int i = 1; i < 8; ++i) {
                int c = (i < 4) ? (lane * 4 + i) : (256 + lane * 4 + (i - 4));
                unsigned long long k2 = packkey(v[i], c);
                if (k2 < m) m = k2;
            }
        }
        #pragma unroll
        for (int o = 32; o; o >>= 1) {
            unsigned long long o2 = __shfl_down(m, o, 64);
            if (o2 < m) m = o2;
        }
        m = __shfl(m, 0, 64);                    // broadcast winner to all lanes
        sCur = (int)(m & 0xFFFFFFFFull);
        if (lane == 0) keys[t] = sCur;
    }
}

// Fused finish, ONE ordinary launch (grid 1 x 256): wave 0 runs the chain,
// block-local __syncthreads (NOT grid sync), then 4 waves write the output.
// out = [sofar(32) | pls(B,TL,J)] with pls[b,tau,j] = PLT[tau][j][s15].
__global__ void k_finish(const float* __restrict__ S0, const float* __restrict__ DOT,
                         const float* __restrict__ PLT, int* __restrict__ keys,
                         float* __restrict__ out) {
    int tid = threadIdx.x;
    if (tid < 64) seq_chain(S0, DOT, keys);      // single proven wave
    __syncthreads();                             // keys visible block-wide

    int s16 = keys[TLn], s15 = keys[TLn - 1];
    int j = tid & 127, h = tid >> 7;             // h: tau-half 0..1
    float val[8];
    #pragma unroll
    for (int tt = 0; tt < 8; ++tt)               // 8 gathers (2KB stride)
        val[tt] = PLT[((size_t)(h * 8 + tt) * Jd + j) * Cn + s15];
    #pragma unroll
    for (int b = 0; b < Bn; ++b)
        #pragma unroll
        for (int tt = 0; tt < 8; ++tt)           // coalesced over j lanes
            out[Bn + ((size_t)b * TLn + h * 8 + tt) * Jd + j] = val[tt];
    if (tid < Bn) out[tid] = (float)s16;
}

extern "C" void kernel_launch(void* const* d_in, const int* in_sizes, int n_in,
                              void* d_out, int out_size, void* d_ws, size_t ws_size,
                              hipStream_t stream) {
    // inputs: 0:x (dead, 32MB), 1:lens (dead), 2:sos, 3:label_seqs, 4:W  (all f32)
    const float* sos = (const float*)d_in[2];
    const float* L   = (const float*)d_in[3];
    const float* W   = (const float*)d_in[4];
    float* out = (float*)d_out;

    // ws: S0(2KB)@0 | keys@2048 | l2T(32KB)@4K | PLT(4MB)@64K | LT(4MB) | DOT(16.8MB)
    const size_t l2Off  = 4096;
    const size_t pltOff = 65536;
    const size_t ltOff  = pltOff + (size_t)TLn * Jd * Cn * sizeof(float);
    const size_t dotOff = ltOff  + (size_t)TLn * Jd * Cn * sizeof(float);
    const size_t need   = dotOff + (size_t)Cn * TLn * Cn * sizeof(float);  // ~25 MB
    char* base = (ws_size >= need) ? (char*)d_ws : (char*)d_in[0];  // x dead, 32 MB
    float* S0   = (float*)base;
    int*   keys = (int*)(base + 2048);
    float* l2T  = (float*)(base + l2Off);
    float* PLT  = (float*)(base + pltOff);
    float* LT   = (float*)(base + ltOff);
    float* DOT  = (float*)(base + dotOff);

    hipLaunchKernelGGL(k_prep3,  dim3(512), dim3(256), 0, stream, L, W, LT, l2T, PLT);
    hipLaunchKernelGGL(k_dot,    dim3(513), dim3(256), 0, stream,
                       LT, PLT, l2T, sos, W, DOT, S0);
    hipLaunchKernelGGL(k_finish, dim3(1),   dim3(256), 0, stream,
                       S0, DOT, PLT, keys, out);
}

// Round 9
// 125.356 us; speedup vs baseline: 1.1585x; 1.0061x over previous
//
#include <hip/hip_runtime.h>

// Problem constants
#define Jd   128   // feature dim
#define Cn   512   // num classes
#define TLn  16    // label seq length
#define Bn   32    // batch

// ---------------------------------------------------------------------------
// Reduction (x, lens dead; batch-uniform trajectory):
//   LT [tau][k][c] = L[c,tau,k]          l2T[tau][c] = ||L[c,tau,:]||^2
//   PLT[tau][j][c] = sum_k W[k][j]*L[c,tau,k]          ( = (L@W)^T )
//   S0[c]          = ||sos@W - L[c,0,:]||^2
//   DOT[s][tau][c] = l2T[tau][c] - 2*sum_j PLT[tau][j][s]*LT[tau][j][c]
//   s_0 = argmin S0;  s_t = argmin_c sum_{tau<t} DOT[s_{t-1}][tau][c]
//   out = [ broadcast_B(s_16) | broadcast_B(PLT[:, :, s_15]) ]
// Round-19: r18's fused k_finish was neutral because its write phase issued
// 65536 scalar stores from one 4-wave block (~6.7us issue time), refunding
// the saved launch gap. Fix the write, keep the fusion: (1) float4 output
// stores (insts 65536->16384); (2) 512 threads = 8 waves for 2x issue width
// and gather latency hiding. Chain + gathered values + all fmaf orders
// byte-identical -> absmax stays 0. prep3/k_dot = exact 122.3us baseline.
// ---------------------------------------------------------------------------

__device__ __forceinline__ unsigned int f2ord(float f) {
    unsigned int u = __float_as_uint(f);
    return (u & 0x80000000u) ? ~u : (u | 0x80000000u);   // monotone total order
}
__device__ __forceinline__ unsigned long long packkey(float v, int c) {
    return ((unsigned long long)f2ord(v) << 32) | (unsigned int)c;
}

// grid = 512 x 256: bid -> tau = bid&15, jh = (bid>>4)&1 (j-half), ct = bid>>5
// (16 c-tiles of 32). Produces PLT[tau][jh*64..+63][c-tile]; jh==0 blocks also
// emit LT + l2T for their c-tile.
__global__ void __launch_bounds__(256, 4)
k_prep3(const float* __restrict__ L, const float* __restrict__ W,
        float* __restrict__ LT, float* __restrict__ l2T,
        float* __restrict__ PLT) {
    __shared__ float Lst[128][36];               // 18 KB transposed L tile [k][c]
    __shared__ float Ws[128][68];                // 34 KB W half [k][j-j0]
    int tid = threadIdx.x, bid = blockIdx.x;
    int tau = bid & 15, jh = (bid >> 4) & 1, c0 = (bid >> 5) * 32;
    int j0 = jh * 64;

    // --- stage Lst (transpose 32 L-rows; coalesced global reads) + l2 ---
    int cr = tid >> 3, oc = tid & 7;             // c-row 0..31, octant
    const float4* src = (const float4*)(L + ((size_t)(c0 + cr) * TLn + tau) * Jd);
    float l2p = 0.f;
    #pragma unroll
    for (int i = 0; i < 4; ++i) {
        float4 v = src[oc * 4 + i];
        int kb = (oc * 4 + i) * 4;
        Lst[kb + 0][cr] = v.x;  Lst[kb + 1][cr] = v.y;
        Lst[kb + 2][cr] = v.z;  Lst[kb + 3][cr] = v.w;
        l2p += v.x * v.x + v.y * v.y + v.z * v.z + v.w * v.w;
    }
    l2p += __shfl_down(l2p, 4, 8);               // reduce over octant (8 lanes/c)
    l2p += __shfl_down(l2p, 2, 8);
    l2p += __shfl_down(l2p, 1, 8);
    if (oc == 0 && jh == 0) l2T[tau * Cn + c0 + cr] = l2p;

    // --- stage Ws: W[k][j0..j0+63], straight coalesced copy ---
    #pragma unroll
    for (int r = 0; r < 8; ++r) {
        int idx = r * 256 + tid;                 // 0..2047 float4s
        int k = idx >> 4, f = idx & 15;
        *(float4*)&Ws[k][f * 4] = *(const float4*)(W + (size_t)k * Jd + j0 + f * 4);
    }
    __syncthreads();

    int c = tid & 31, jq = tid >> 5;             // c lane (coalesced), 8 j-groups

    // --- LT emit (jh==0 only): b32 reads conflict-free, 128B-chunk stores ---
    if (jh == 0) {
        #pragma unroll
        for (int k = jq; k < Jd; k += 8)
            LT[((size_t)tau * Jd + k) * Cn + c0 + c] = Lst[k][c];
    }

    // --- GEMM: PLT[tau][j0+jq*8+i][c0+c] = sum_k Ws[k][jq*8+i] * Lst[k][c] ---
    float acc[8] = {};
    #pragma unroll 4
    for (int k = 0; k < Jd; ++k) {               // ascending k: same sum order
        float a = Lst[k][c];                     // b32, banks all distinct (pitch 36)
        float4 w0 = *(const float4*)&Ws[k][jq * 8];      // 32-lane broadcast b128
        float4 w1 = *(const float4*)&Ws[k][jq * 8 + 4];
        acc[0] = fmaf(a, w0.x, acc[0]);
        acc[1] = fmaf(a, w0.y, acc[1]);
        acc[2] = fmaf(a, w0.z, acc[2]);
        acc[3] = fmaf(a, w0.w, acc[3]);
        acc[4] = fmaf(a, w1.x, acc[4]);
        acc[5] = fmaf(a, w1.y, acc[5]);
        acc[6] = fmaf(a, w1.z, acc[6]);
        acc[7] = fmaf(a, w1.w, acc[7]);
    }
    #pragma unroll
    for (int i = 0; i < 8; ++i)                  // two 128B chunks per store inst
        PLT[((size_t)tau * Jd + j0 + jq * 8 + i) * Cn + c0 + c] = acc[i];
}

// grid = 513 x 256, LDS-staged GEMM, 3 blocks/CU (144KB LDS). bid<512:
// tau = bid&15, st = (bid>>4)&7 (64 s), cq = bid>>7 (128 c). K in 2 j-halves;
// micro 4s x 8c. bid==512: S0.   [exact baseline structure, 122.3us verified]
__global__ void __launch_bounds__(256, 3)
k_dot(const float* __restrict__ LT, const float* __restrict__ PLT,
      const float* __restrict__ l2T,
      const float* __restrict__ sos, const float* __restrict__ W,
      float* __restrict__ DOT, float* __restrict__ S0) {
    __shared__ float As[64][64];                 // 16 KB  [j][s]
    __shared__ float Bs[64][128];                // 32 KB  [j][c]
    int tid = threadIdx.x, bid = blockIdx.x;

    if (bid == 512) {                            // ---- S0 path ----
        float* pred0 = &As[0][0];
        if (tid < Jd) {
            float a = 0.f;
            for (int k = 0; k < Jd; ++k) a = fmaf(sos[k], W[k * Jd + tid], a);
            pred0[tid] = a;
        }
        __syncthreads();
        float a0 = 0.f, a1 = 0.f;
        for (int jj = 0; jj < Jd; ++jj) {
            float p = pred0[jj];
            float d0 = p - LT[(size_t)jj * Cn + tid];        // tau = 0 plane
            float d1 = p - LT[(size_t)jj * Cn + tid + 256];
            a0 = fmaf(d0, d0, a0);
            a1 = fmaf(d1, d1, a1);
        }
        S0[tid] = a0;  S0[tid + 256] = a1;
        return;
    }

    int tau = bid & 15, st = (bid >> 4) & 7, cq = bid >> 7;
    int s0 = st * 64, c0 = cq * 128;
    int sg = tid >> 4, cg = tid & 15;            // 16x16 threads

    float acc[4][8] = {};                        // 4 s x (4+4) c
    for (int h = 0; h < 2; ++h) {                // j-halves
        __syncthreads();
        // stage A half: 64 j-rows x 64 s  (coalesced global, conflict-free LDS)
        const float4* Asrc = (const float4*)(PLT + ((size_t)tau * Jd + h * 64) * Cn + s0);
        #pragma unroll
        for (int i = 0; i < 4; ++i) {
            int flat = i * 256 + tid;            // 0..1023 float4s
            int row = flat >> 4, col = flat & 15;
            *(float4*)&As[row][col * 4] = Asrc[(size_t)row * (Cn / 4) + col];
        }
        // stage B half: 64 j-rows x 128 c
        const float4* Bsrc = (const float4*)(LT + ((size_t)tau * Jd + h * 64) * Cn + c0);
        #pragma unroll
        for (int i = 0; i < 8; ++i) {
            int flat = i * 256 + tid;            // 0..2047 float4s
            int row = flat >> 5, col = flat & 31;
            *(float4*)&Bs[row][col * 4] = Bsrc[(size_t)row * (Cn / 4) + col];
        }
        __syncthreads();
        #pragma unroll 4
        for (int j = 0; j < 64; ++j) {           // ascending j: same sum order
            float4 a  = *(const float4*)&As[j][sg * 4];       // broadcast, no conflict
            float4 b0 = *(const float4*)&Bs[j][cg * 4];       // 2-way (free)
            float4 b1 = *(const float4*)&Bs[j][64 + cg * 4];  // 2-way (free)
            float av[4] = {a.x, a.y, a.z, a.w};
            float bv[8] = {b0.x, b0.y, b0.z, b0.w, b1.x, b1.y, b1.z, b1.w};
            #pragma unroll
            for (int i = 0; i < 4; ++i)
                #pragma unroll
                for (int q = 0; q < 8; ++q)
                    acc[i][q] = fmaf(av[i], bv[q], acc[i][q]);
        }
    }

    float4 l2a = *(const float4*)(l2T + tau * Cn + c0 + cg * 4);
    float4 l2b = *(const float4*)(l2T + tau * Cn + c0 + 64 + cg * 4);
    #pragma unroll
    for (int i = 0; i < 4; ++i) {
        int s = s0 + sg * 4 + i;
        float* dst = DOT + ((size_t)s * TLn + tau) * Cn + c0;
        float4 v0 = {l2a.x - 2.f * acc[i][0], l2a.y - 2.f * acc[i][1],
                     l2a.z - 2.f * acc[i][2], l2a.w - 2.f * acc[i][3]};
        float4 v1 = {l2b.x - 2.f * acc[i][4], l2b.y - 2.f * acc[i][5],
                     l2b.z - 2.f * acc[i][6], l2b.w - 2.f * acc[i][7]};
        *(float4*)(dst + cg * 4) = v0;           // 256B contiguous per 16 lanes
        *(float4*)(dst + 64 + cg * 4) = v1;
    }
}

// Single-wave argmin chain (proven absmax-0): 17 steps, float4 loads (8 c
// per lane), no barriers/LDS, pure in-wave shuffle reduce.
__device__ __forceinline__ void seq_chain(const float* __restrict__ S0,
                                          const float* __restrict__ DOT,
                                          int* __restrict__ keys) {
    int lane = threadIdx.x;                      // 0..63
    int sCur = 0;
    for (int t = 0; t <= TLn; ++t) {
        unsigned long long m;
        if (t == 0) {
            float4 v0 = *(const float4*)(S0 + lane * 4);
            float4 v1 = *(const float4*)(S0 + 256 + lane * 4);
            float v[8] = {v0.x, v0.y, v0.z, v0.w, v1.x, v1.y, v1.z, v1.w};
            m = packkey(v[0], lane * 4);
            #pragma unroll
            for (int i = 1; i < 8; ++i) {
                int c = (i < 4) ? (lane * 4 + i) : (256 + lane * 4 + (i - 4));
                unsigned long long k2 = packkey(v[i], c);
                if (k2 < m) m = k2;
            }
        } else {
            const float* base = DOT + (size_t)sCur * TLn * Cn;
            float4 s0v = {0.f, 0.f, 0.f, 0.f}, s1v = {0.f, 0.f, 0.f, 0.f};
            #pragma unroll
            for (int tau = 0; tau < TLn; ++tau) {            // 32 independent b128
                float4 w0 = *(const float4*)(base + (size_t)tau * Cn + lane * 4);
                float4 w1 = *(const float4*)(base + (size_t)tau * Cn + 256 + lane * 4);
                float mk = (tau < t) ? 1.f : 0.f;            // ascending tau chain
                s0v.x = fmaf(w0.x, mk, s0v.x);  s0v.y = fmaf(w0.y, mk, s0v.y);
                s0v.z = fmaf(w0.z, mk, s0v.z);  s0v.w = fmaf(w0.w, mk, s0v.w);
                s1v.x = fmaf(w1.x, mk, s1v.x);  s1v.y = fmaf(w1.y, mk, s1v.y);
                s1v.z = fmaf(w1.z, mk, s1v.z);  s1v.w = fmaf(w1.w, mk, s1v.w);
            }
            float v[8] = {s0v.x, s0v.y, s0v.z, s0v.w, s1v.x, s1v.y, s1v.z, s1v.w};
            m = packkey(v[0], lane * 4);
            #pragma unroll
            for (int i = 1; i < 8; ++i) {
                int c = (i < 4) ? (lane * 4 + i) : (256 + lane * 4 + (i - 4));
                unsigned long long k2 = packkey(v[i], c);
                if (k2 < m) m = k2;
            }
        }
        #pragma unroll
        for (int o = 32; o; o >>= 1) {
            unsigned long long o2 = __shfl_down(m, o, 64);
            if (o2 < m) m = o2;
        }
        m = __shfl(m, 0, 64);                    // broadcast winner to all lanes
        sCur = (int)(m & 0xFFFFFFFFull);
        if (lane == 0) keys[t] = sCur;
    }
}

// Fused finish, ONE ordinary launch (grid 1 x 512 = 8 waves): wave 0 runs
// the chain, block-local __syncthreads, then all 8 waves write the output
// with float4 stores. Thread owns one (tau, j-quad): gather 4 PLT scalars
// (identical values to k_out's gathers), pack, store 32 dwordx4 (one per b).
__global__ void __launch_bounds__(512, 1)
k_finish(const float* __restrict__ S0, const float* __restrict__ DOT,
         const float* __restrict__ PLT, int* __restrict__ keys,
         float* __restrict__ out) {
    int tid = threadIdx.x;
    if (tid < 64) seq_chain(S0, DOT, keys);      // single proven wave
    __syncthreads();                             // keys visible block-wide

    int s16 = keys[TLn], s15 = keys[TLn - 1];
    int tau = tid >> 5, jq = tid & 31;           // 16 taus x 32 j-quads = 512
    float4 v;
    v.x = PLT[((size_t)tau * Jd + jq * 4 + 0) * Cn + s15];
    v.y = PLT[((size_t)tau * Jd + jq * 4 + 1) * Cn + s15];
    v.z = PLT[((size_t)tau * Jd + jq * 4 + 2) * Cn + s15];
    v.w = PLT[((size_t)tau * Jd + jq * 4 + 3) * Cn + s15];
    #pragma unroll
    for (int b = 0; b < Bn; ++b)                 // 32 dwordx4, coalesced over jq
        *(float4*)(out + Bn + ((size_t)b * TLn + tau) * Jd + jq * 4) = v;
    if (tid < Bn) out[tid] = (float)s16;
}

extern "C" void kernel_launch(void* const* d_in, const int* in_sizes, int n_in,
                              void* d_out, int out_size, void* d_ws, size_t ws_size,
                              hipStream_t stream) {
    // inputs: 0:x (dead, 32MB), 1:lens (dead), 2:sos, 3:label_seqs, 4:W  (all f32)
    const float* sos = (const float*)d_in[2];
    const float* L   = (const float*)d_in[3];
    const float* W   = (const float*)d_in[4];
    float* out = (float*)d_out;

    // ws: S0(2KB)@0 | keys@2048 | l2T(32KB)@4K | PLT(4MB)@64K | LT(4MB) | DOT(16.8MB)
    const size_t l2Off  = 4096;
    const size_t pltOff = 65536;
    const size_t ltOff  = pltOff + (size_t)TLn * Jd * Cn * sizeof(float);
    const size_t dotOff = ltOff  + (size_t)TLn * Jd * Cn * sizeof(float);
    const size_t need   = dotOff + (size_t)Cn * TLn * Cn * sizeof(float);  // ~25 MB
    char* base = (ws_size >= need) ? (char*)d_ws : (char*)d_in[0];  // x dead, 32 MB
    float* S0   = (float*)base;
    int*   keys = (int*)(base + 2048);
    float* l2T  = (float*)(base + l2Off);
    float* PLT  = (float*)(base + pltOff);
    float* LT   = (float*)(base + ltOff);
    float* DOT  = (float*)(base + dotOff);

    hipLaunchKernelGGL(k_prep3,  dim3(512), dim3(256), 0, stream, L, W, LT, l2T, PLT);
    hipLaunchKernelGGL(k_dot,    dim3(513), dim3(256), 0, stream,
                       LT, PLT, l2T, sos, W, DOT, S0);
    hipLaunchKernelGGL(k_finish, dim3(1),   dim3(512), 0, stream,
                       S0, DOT, PLT, keys, out);
}

// Round 11
// 123.204 us; speedup vs baseline: 1.1787x; 1.0175x over previous
//
#include <hip/hip_runtime.h>

// Problem constants
#define Jd   128   // feature dim
#define Cn   512   // num classes
#define TLn  16    // label seq length
#define Bn   32    // batch

// ---------------------------------------------------------------------------
// Reduction (x, lens dead; batch-uniform trajectory):
//   LT [tau][k][c] = L[c,tau,k]          l2T[tau][c] = ||L[c,tau,:]||^2
//   PLT[tau][j][c] = sum_k W[k][j]*L[c,tau,k]          ( = (L@W)^T )
//   S0[c]          = ||sos@W - L[c,0,:]||^2
//   DOT[s][tau][c] = l2T[tau][c] - 2*sum_j PLT[tau][j][s]*LT[tau][j][c]
//   s_0 = argmin S0;  s_t = argmin_c sum_{tau<t} DOT[s_{t-1}][tau][c]
//   out = [ broadcast_B(s_16) | broadcast_B(PLT[:, :, s_15]) ]
// Round-21 (resubmit of round-20; bench was a container infra failure, same
// signature as r12/r16 infra failures which both passed on resubmit):
// the 13us serial k_seq chain (17 DEPENDENT 32KB-gather+reduce steps) is
// replaced by k_tab: NEXT[s][t] = argmin_c prefix_t(DOT[s][:,c]) depends
// only on (s,t) -> computed by 512 concurrent blocks (~4us wall); the chain
// becomes 16 dependent int lookups in k_finish (~2us). Min-reduction is
// order-independent -> same winners; prefix adds are the same ascending
// acc+v sequence (fmaf(v,1,acc)==acc+v; fmaf(v,0,acc)==acc) -> absmax 0.
// prep3/k_dot byte-identical to the 122.3us baseline.
// ---------------------------------------------------------------------------

__device__ __forceinline__ unsigned int f2ord(float f) {
    unsigned int u = __float_as_uint(f);
    return (u & 0x80000000u) ? ~u : (u | 0x80000000u);   // monotone total order
}
__device__ __forceinline__ unsigned long long packkey(float v, int c) {
    return ((unsigned long long)f2ord(v) << 32) | (unsigned int)c;
}

// grid = 512 x 256: bid -> tau = bid&15, jh = (bid>>4)&1 (j-half), ct = bid>>5
// (16 c-tiles of 32). Produces PLT[tau][jh*64..+63][c-tile]; jh==0 blocks also
// emit LT + l2T for their c-tile.
__global__ void __launch_bounds__(256, 4)
k_prep3(const float* __restrict__ L, const float* __restrict__ W,
        float* __restrict__ LT, float* __restrict__ l2T,
        float* __restrict__ PLT) {
    __shared__ float Lst[128][36];               // 18 KB transposed L tile [k][c]
    __shared__ float Ws[128][68];                // 34 KB W half [k][j-j0]
    int tid = threadIdx.x, bid = blockIdx.x;
    int tau = bid & 15, jh = (bid >> 4) & 1, c0 = (bid >> 5) * 32;
    int j0 = jh * 64;

    // --- stage Lst (transpose 32 L-rows; coalesced global reads) + l2 ---
    int cr = tid >> 3, oc = tid & 7;             // c-row 0..31, octant
    const float4* src = (const float4*)(L + ((size_t)(c0 + cr) * TLn + tau) * Jd);
    float l2p = 0.f;
    #pragma unroll
    for (int i = 0; i < 4; ++i) {
        float4 v = src[oc * 4 + i];
        int kb = (oc * 4 + i) * 4;
        Lst[kb + 0][cr] = v.x;  Lst[kb + 1][cr] = v.y;
        Lst[kb + 2][cr] = v.z;  Lst[kb + 3][cr] = v.w;
        l2p += v.x * v.x + v.y * v.y + v.z * v.z + v.w * v.w;
    }
    l2p += __shfl_down(l2p, 4, 8);               // reduce over octant (8 lanes/c)
    l2p += __shfl_down(l2p, 2, 8);
    l2p += __shfl_down(l2p, 1, 8);
    if (oc == 0 && jh == 0) l2T[tau * Cn + c0 + cr] = l2p;

    // --- stage Ws: W[k][j0..j0+63], straight coalesced copy ---
    #pragma unroll
    for (int r = 0; r < 8; ++r) {
        int idx = r * 256 + tid;                 // 0..2047 float4s
        int k = idx >> 4, f = idx & 15;
        *(float4*)&Ws[k][f * 4] = *(const float4*)(W + (size_t)k * Jd + j0 + f * 4);
    }
    __syncthreads();

    int c = tid & 31, jq = tid >> 5;             // c lane (coalesced), 8 j-groups

    // --- LT emit (jh==0 only): b32 reads conflict-free, 128B-chunk stores ---
    if (jh == 0) {
        #pragma unroll
        for (int k = jq; k < Jd; k += 8)
            LT[((size_t)tau * Jd + k) * Cn + c0 + c] = Lst[k][c];
    }

    // --- GEMM: PLT[tau][j0+jq*8+i][c0+c] = sum_k Ws[k][jq*8+i] * Lst[k][c] ---
    float acc[8] = {};
    #pragma unroll 4
    for (int k = 0; k < Jd; ++k) {               // ascending k: same sum order
        float a = Lst[k][c];                     // b32, banks all distinct (pitch 36)
        float4 w0 = *(const float4*)&Ws[k][jq * 8];      // 32-lane broadcast b128
        float4 w1 = *(const float4*)&Ws[k][jq * 8 + 4];
        acc[0] = fmaf(a, w0.x, acc[0]);
        acc[1] = fmaf(a, w0.y, acc[1]);
        acc[2] = fmaf(a, w0.z, acc[2]);
        acc[3] = fmaf(a, w0.w, acc[3]);
        acc[4] = fmaf(a, w1.x, acc[4]);
        acc[5] = fmaf(a, w1.y, acc[5]);
        acc[6] = fmaf(a, w1.z, acc[6]);
        acc[7] = fmaf(a, w1.w, acc[7]);
    }
    #pragma unroll
    for (int i = 0; i < 8; ++i)                  // two 128B chunks per store inst
        PLT[((size_t)tau * Jd + j0 + jq * 8 + i) * Cn + c0 + c] = acc[i];
}

// grid = 513 x 256, LDS-staged GEMM, 3 blocks/CU (144KB LDS). bid<512:
// tau = bid&15, st = (bid>>4)&7 (64 s), cq = bid>>7 (128 c). K in 2 j-halves;
// micro 4s x 8c. bid==512: S0.   [exact baseline structure, 122.3us verified]
__global__ void __launch_bounds__(256, 3)
k_dot(const float* __restrict__ LT, const float* __restrict__ PLT,
      const float* __restrict__ l2T,
      const float* __restrict__ sos, const float* __restrict__ W,
      float* __restrict__ DOT, float* __restrict__ S0) {
    __shared__ float As[64][64];                 // 16 KB  [j][s]
    __shared__ float Bs[64][128];                // 32 KB  [j][c]
    int tid = threadIdx.x, bid = blockIdx.x;

    if (bid == 512) {                            // ---- S0 path ----
        float* pred0 = &As[0][0];
        if (tid < Jd) {
            float a = 0.f;
            for (int k = 0; k < Jd; ++k) a = fmaf(sos[k], W[k * Jd + tid], a);
            pred0[tid] = a;
        }
        __syncthreads();
        float a0 = 0.f, a1 = 0.f;
        for (int jj = 0; jj < Jd; ++jj) {
            float p = pred0[jj];
            float d0 = p - LT[(size_t)jj * Cn + tid];        // tau = 0 plane
            float d1 = p - LT[(size_t)jj * Cn + tid + 256];
            a0 = fmaf(d0, d0, a0);
            a1 = fmaf(d1, d1, a1);
        }
        S0[tid] = a0;  S0[tid + 256] = a1;
        return;
    }

    int tau = bid & 15, st = (bid >> 4) & 7, cq = bid >> 7;
    int s0 = st * 64, c0 = cq * 128;
    int sg = tid >> 4, cg = tid & 15;            // 16x16 threads

    float acc[4][8] = {};                        // 4 s x (4+4) c
    for (int h = 0; h < 2; ++h) {                // j-halves
        __syncthreads();
        // stage A half: 64 j-rows x 64 s  (coalesced global, conflict-free LDS)
        const float4* Asrc = (const float4*)(PLT + ((size_t)tau * Jd + h * 64) * Cn + s0);
        #pragma unroll
        for (int i = 0; i < 4; ++i) {
            int flat = i * 256 + tid;            // 0..1023 float4s
            int row = flat >> 4, col = flat & 15;
            *(float4*)&As[row][col * 4] = Asrc[(size_t)row * (Cn / 4) + col];
        }
        // stage B half: 64 j-rows x 128 c
        const float4* Bsrc = (const float4*)(LT + ((size_t)tau * Jd + h * 64) * Cn + c0);
        #pragma unroll
        for (int i = 0; i < 8; ++i) {
            int flat = i * 256 + tid;            // 0..2047 float4s
            int row = flat >> 5, col = flat & 31;
            *(float4*)&Bs[row][col * 4] = Bsrc[(size_t)row * (Cn / 4) + col];
        }
        __syncthreads();
        #pragma unroll 4
        for (int j = 0; j < 64; ++j) {           // ascending j: same sum order
            float4 a  = *(const float4*)&As[j][sg * 4];       // broadcast, no conflict
            float4 b0 = *(const float4*)&Bs[j][cg * 4];       // 2-way (free)
            float4 b1 = *(const float4*)&Bs[j][64 + cg * 4];  // 2-way (free)
            float av[4] = {a.x, a.y, a.z, a.w};
            float bv[8] = {b0.x, b0.y, b0.z, b0.w, b1.x, b1.y, b1.z, b1.w};
            #pragma unroll
            for (int i = 0; i < 4; ++i)
                #pragma unroll
                for (int q = 0; q < 8; ++q)
                    acc[i][q] = fmaf(av[i], bv[q], acc[i][q]);
        }
    }

    float4 l2a = *(const float4*)(l2T + tau * Cn + c0 + cg * 4);
    float4 l2b = *(const float4*)(l2T + tau * Cn + c0 + 64 + cg * 4);
    #pragma unroll
    for (int i = 0; i < 4; ++i) {
        int s = s0 + sg * 4 + i;
        float* dst = DOT + ((size_t)s * TLn + tau) * Cn + c0;
        float4 v0 = {l2a.x - 2.f * acc[i][0], l2a.y - 2.f * acc[i][1],
                     l2a.z - 2.f * acc[i][2], l2a.w - 2.f * acc[i][3]};
        float4 v1 = {l2b.x - 2.f * acc[i][4], l2b.y - 2.f * acc[i][5],
                     l2b.z - 2.f * acc[i][6], l2b.w - 2.f * acc[i][7]};
        *(float4*)(dst + cg * 4) = v0;           // 256B contiguous per 16 lanes
        *(float4*)(dst + 64 + cg * 4) = v1;
    }
}

// grid = 513 x 256. bid<512: block per s — load DOT[s] (16 tau x 512 c,
// coalesced, L2/L3-resident), ascending-tau prefix per c (same add sequence
// as the old masked chain), 16 block-wide packkey-min reductions (min is
// order-independent -> same winner as the serial chain's reduce). Writes
// NEXT[s][t-1] for t=1..16. bid==512: argmin S0 -> keys[0].
__global__ void __launch_bounds__(256, 4)
k_tab(const float* __restrict__ DOT, const float* __restrict__ S0,
      int* __restrict__ NEXT, int* __restrict__ keys) {
    __shared__ unsigned long long red[4];
    int tid = threadIdx.x, bid = blockIdx.x;
    int w = tid >> 6, lane = tid & 63;

    if (bid == 512) {                            // ---- argmin S0 -> keys[0] ----
        unsigned long long m = packkey(S0[tid], tid);
        unsigned long long k2 = packkey(S0[tid + 256], tid + 256);
        if (k2 < m) m = k2;
        #pragma unroll
        for (int o = 32; o; o >>= 1) {
            unsigned long long o2 = __shfl_down(m, o, 64);
            if (o2 < m) m = o2;
        }
        if (lane == 0) red[w] = m;
        __syncthreads();
        if (tid == 0) {
            unsigned long long b = red[0];
            #pragma unroll
            for (int i = 1; i < 4; ++i) if (red[i] < b) b = red[i];
            keys[0] = (int)(b & 0xFFFFFFFFull);
        }
        return;
    }

    const float* base = DOT + (size_t)bid * TLn * Cn;
    float v0[TLn], v1[TLn];
    #pragma unroll
    for (int tau = 0; tau < TLn; ++tau) {        // 32 independent coalesced loads
        v0[tau] = base[(size_t)tau * Cn + tid];
        v1[tau] = base[(size_t)tau * Cn + tid + 256];
    }
    float a0 = 0.f, a1 = 0.f;
    for (int t = 1; t <= TLn; ++t) {
        a0 += v0[t - 1];                         // ascending tau: same sum values
        a1 += v1[t - 1];                         // as the old masked-fmaf chain
        unsigned long long m = packkey(a0, tid);
        unsigned long long k2 = packkey(a1, tid + 256);
        if (k2 < m) m = k2;
        #pragma unroll
        for (int o = 32; o; o >>= 1) {
            unsigned long long o2 = __shfl_down(m, o, 64);
            if (o2 < m) m = o2;
        }
        if (lane == 0) red[w] = m;
        __syncthreads();
        if (tid == 0) {
            unsigned long long b = red[0];
            #pragma unroll
            for (int i = 1; i < 4; ++i) if (red[i] < b) b = red[i];
            NEXT[bid * TLn + (t - 1)] = (int)(b & 0xFFFFFFFFull);
        }
        __syncthreads();                         // red reused next t
    }
}

// Fused finish, grid 1 x 512 (8 waves): thread 0 walks the 16-entry lookup
// chain (dependent int loads, ~2us), syncthreads, then all 8 waves do the
// r19-proven vectorized output write (float4 stores, coalesced over j).
__global__ void __launch_bounds__(512, 1)
k_finish(const float* __restrict__ PLT, const int* __restrict__ NEXT,
         int* __restrict__ keys, float* __restrict__ out) {
    int tid = threadIdx.x;
    if (tid == 0) {
        int sCur = keys[0];                      // written by k_tab block 512
        #pragma unroll
        for (int t = 1; t <= TLn; ++t) {
            sCur = NEXT[sCur * TLn + (t - 1)];   // dependent L2/L3 lookups
            keys[t] = sCur;
        }
    }
    __syncthreads();                             // keys visible block-wide

    int s15 = keys[TLn - 1];
    int tau = tid >> 5, jq = tid & 31;           // 16 taus x 32 j-quads = 512
    float4 v;
    v.x = PLT[((size_t)tau * Jd + jq * 4 + 0) * Cn + s15];
    v.y = PLT[((size_t)tau * Jd + jq * 4 + 1) * Cn + s15];
    v.z = PLT[((size_t)tau * Jd + jq * 4 + 2) * Cn + s15];
    v.w = PLT[((size_t)tau * Jd + jq * 4 + 3) * Cn + s15];
    #pragma unroll
    for (int b = 0; b < Bn; ++b)                 // 32 dwordx4, coalesced over jq
        *(float4*)(out + Bn + ((size_t)b * TLn + tau) * Jd + jq * 4) = v;
    if (tid < Bn) out[tid] = (float)keys[TLn];
}

extern "C" void kernel_launch(void* const* d_in, const int* in_sizes, int n_in,
                              void* d_out, int out_size, void* d_ws, size_t ws_size,
                              hipStream_t stream) {
    // inputs: 0:x (dead, 32MB), 1:lens (dead), 2:sos, 3:label_seqs, 4:W  (all f32)
    const float* sos = (const float*)d_in[2];
    const float* L   = (const float*)d_in[3];
    const float* W   = (const float*)d_in[4];
    float* out = (float*)d_out;

    // ws: S0(2KB)@0 | keys@2048 | l2T(32KB)@4K | PLT(4MB)@64K | LT(4MB) |
    //     DOT(16.8MB) | NEXT(32KB)
    const size_t l2Off   = 4096;
    const size_t pltOff  = 65536;
    const size_t ltOff   = pltOff + (size_t)TLn * Jd * Cn * sizeof(float);
    const size_t dotOff  = ltOff  + (size_t)TLn * Jd * Cn * sizeof(float);
    const size_t nextOff = dotOff + (size_t)Cn * TLn * Cn * sizeof(float);
    const size_t need    = nextOff + (size_t)Cn * TLn * sizeof(int);   // ~25 MB
    char* base = (ws_size >= need) ? (char*)d_ws : (char*)d_in[0];  // x dead, 32 MB
    float* S0   = (float*)base;
    int*   keys = (int*)(base + 2048);
    float* l2T  = (float*)(base + l2Off);
    float* PLT  = (float*)(base + pltOff);
    float* LT   = (float*)(base + ltOff);
    float* DOT  = (float*)(base + dotOff);
    int*   NEXT = (int*)(base + nextOff);

    hipLaunchKernelGGL(k_prep3,  dim3(512), dim3(256), 0, stream, L, W, LT, l2T, PLT);
    hipLaunchKernelGGL(k_dot,    dim3(513), dim3(256), 0, stream,
                       LT, PLT, l2T, sos, W, DOT, S0);
    hipLaunchKernelGGL(k_tab,    dim3(513), dim3(256), 0, stream,
                       DOT, S0, NEXT, keys);
    hipLaunchKernelGGL(k_finish, dim3(1),   dim3(512), 0, stream,
                       PLT, NEXT, keys, out);
}